// Round 11
// baseline (809.893 us; speedup 1.0000x reference)
//
#include <hip/hip_runtime.h>
#include <hip/hip_fp16.h>
#include <cstdint>

#define HD    128
#define OUTD  10
#define NG    512
#define KSTEPS 10

typedef unsigned short ushort_t;
typedef unsigned int   uint_t;
typedef unsigned char  uchar_t;
typedef float vf2 __attribute__((ext_vector_type(2)));

// bf16 helpers (x/h stored as bf16: REQUIRED — propagated values reach ~1e10,
// f16 overflows at 65504 (R9 failure). f32 accumulate everywhere.)
__device__ __forceinline__ float bf_lo(uint_t u) { return __uint_as_float(u << 16); }
__device__ __forceinline__ float bf_hi(uint_t u) { return __uint_as_float(u & 0xFFFF0000u); }
__device__ __forceinline__ uint_t f2bf_rne(float f) {          // 16-bit result
    uint_t u = __float_as_uint(f);
    return (u + 0x7FFFu + ((u >> 16) & 1u)) >> 16;
}
__device__ __forceinline__ uint_t pack_bf2(float lo, float hi) {
    return f2bf_rne(lo) | (f2bf_rne(hi) << 16);
}

// packed f32 FMA (CDNA VOP3P): d = a*b + c on both lanes of the pair.
__device__ __forceinline__ vf2 pk_fma(vf2 a, vf2 b, vf2 c) {
    vf2 d;
    asm("v_pk_fma_f32 %0, %1, %2, %3" : "=v"(d) : "v"(a), "v"(b), "v"(c));
    return d;
}

// ---------------------------------------------------------------------------
// 1) Collapse the two linear layers: Wc = W1@W2, bc = b1@W2 + b2
// ---------------------------------------------------------------------------
__global__ void wc_kernel(const float* __restrict__ W1, const float* __restrict__ b1,
                          const float* __restrict__ W2, const float* __restrict__ b2,
                          float* __restrict__ Wc, float* __restrict__ bc) {
    int idx = blockIdx.x * 256 + threadIdx.x;      // 0..16383
    int d = idx >> 7, j = idx & 127;
    float s = 0.f;
    for (int t = 0; t < HD; t++) s += W1[d * HD + t] * W2[t * HD + j];
    Wc[idx] = s;
    if (idx < HD) {
        float sb = b2[idx];
        for (int t = 0; t < HD; t++) sb += b1[t] * W2[t * HD + idx];
        bc[idx] = sb;
    }
}

// ---------------------------------------------------------------------------
// 2) h[n][j] = sum_d feat[d][n]*Wc[d][j] + bc[j] -> bf16 [N][128]
//    Register-tiled GEMM, 64 nodes x 128 dims per block (8j x 4n / thread).
//    (R7: FNT=128 -> 391 blocks -> 14% occupancy; FNT=64 fixed it.)
// ---------------------------------------------------------------------------
#define FNT 64                  // nodes per block
#define FDC 32                  // d-chunk
__global__ void __launch_bounds__(256) feat_kernel(
        const float* __restrict__ feat, const float* __restrict__ Wc,
        const float* __restrict__ bc, ushort_t* __restrict__ h, int N) {
    __shared__ float fch[FDC * FNT];          // [dd][n]  8 KB
    __shared__ float wch[FDC * HD];           // [dd][j] 16 KB
    int t = threadIdx.x;
    int nb0 = blockIdx.x * FNT;
    int tj = t & 15, tn = t >> 4;             // 16 j-groups x 16 n-groups
    int j0 = tj * 8, n0 = tn * 4;             // 8 j x 4 n per thread

    float acc[4][8];
    #pragma unroll
    for (int a = 0; a < 4; a++)
        #pragma unroll
        for (int b = 0; b < 8; b++) acc[a][b] = 0.f;

    for (int dc = 0; dc < HD; dc += FDC) {
        #pragma unroll
        for (int k = 0; k < (FDC * FNT) / 256; k++) {    // 8 iters
            int l = k * 256 + t;
            int dd = l >> 6, n = l & 63;
            int nn = nb0 + n;
            fch[l] = (nn < N) ? feat[(size_t)(dc + dd) * N + nn] : 0.f;
        }
        #pragma unroll
        for (int k = 0; k < (FDC * HD) / 256; k++) {     // 16 iters
            int l = k * 256 + t;
            int dd = l >> 7, j = l & 127;
            wch[l] = Wc[(dc + dd) * HD + j];
        }
        __syncthreads();
        for (int dd = 0; dd < FDC; dd++) {
            const float* fr = &fch[dd * FNT + n0];
            const float* wr = &wch[dd * HD + j0];
            float fv[4], wv[8];
            #pragma unroll
            for (int a = 0; a < 4; a++) fv[a] = fr[a];
            #pragma unroll
            for (int b = 0; b < 8; b++) wv[b] = wr[b];
            #pragma unroll
            for (int a = 0; a < 4; a++)
                #pragma unroll
                for (int b = 0; b < 8; b++) acc[a][b] += fv[a] * wv[b];
        }
        __syncthreads();
    }

    float bv[8];
    #pragma unroll
    for (int b = 0; b < 8; b++) bv[b] = bc[j0 + b];
    #pragma unroll
    for (int a = 0; a < 4; a++) {
        int n = nb0 + n0 + a;
        if (n < N) {
            uint4 ov;
            ov.x = pack_bf2(acc[a][0] + bv[0], acc[a][1] + bv[1]);
            ov.y = pack_bf2(acc[a][2] + bv[2], acc[a][3] + bv[3]);
            ov.z = pack_bf2(acc[a][4] + bv[4], acc[a][5] + bv[5]);
            ov.w = pack_bf2(acc[a][6] + bv[6], acc[a][7] + bv[7]);
            *(uint4*)(h + (size_t)n * HD + j0) = ov;
        }
    }
}

// ---------------------------------------------------------------------------
// 3) CSR build via two-level bucket sort (NO global per-node atomics).
// ---------------------------------------------------------------------------

// S1: global bucket sizes (LDS hist, then one atomic per nonzero bucket/block)
__global__ void __launch_bounds__(256) bcount_kernel(
        const int* __restrict__ ei, int* __restrict__ gbhist, int E, int chunk) {
    __shared__ int lh[256];
    int b = blockIdx.x, t = threadIdx.x;
    lh[t] = 0;
    __syncthreads();
    int lo = b * chunk, hi = min(E, lo + chunk);
    for (int i = lo + t; i < hi; i += 256) atomicAdd(&lh[ei[E + i] >> 8], 1);
    __syncthreads();
    if (lh[t]) atomicAdd(&gbhist[t], lh[t]);
}

// S2: exclusive scan of bucket sizes -> bucket_base[0..NBK], bcursor init
__global__ void bscan_kernel(const int* __restrict__ gbhist, int* __restrict__ bucket_base,
                             int* __restrict__ bcursor, int NBK, int E) {
    __shared__ int sm[256];
    int t = threadIdx.x;
    int v = (t < NBK) ? gbhist[t] : 0;
    sm[t] = v;
    __syncthreads();
    for (int off = 1; off < 256; off <<= 1) {
        int u = (t >= off) ? sm[t - off] : 0;
        __syncthreads();
        sm[t] += u;
        __syncthreads();
    }
    int excl = sm[t] - v;
    if (t < NBK) { bucket_base[t] = excl; bcursor[t] = excl; }
    if (t == 0) bucket_base[NBK] = E;
}

// S3: scatter edges into bucket-ordered intermediate (rec + low-byte of dst).
// Record: (src << 16) | bf16(weight) — bf16 w decodes with ONE shift in prop.
__global__ void __launch_bounds__(256) bscatter_kernel(
        const int* __restrict__ ei, const float* __restrict__ ewt,
        int* __restrict__ bcursor, uint_t* __restrict__ rec_tmp,
        uchar_t* __restrict__ dlo_tmp, int E, int chunk) {
    __shared__ int lh[256];
    __shared__ int lcur[256];
    int b = blockIdx.x, t = threadIdx.x;
    lh[t] = 0;
    __syncthreads();
    int lo = b * chunk, hi = min(E, lo + chunk);
    for (int i = lo + t; i < hi; i += 256) atomicAdd(&lh[ei[E + i] >> 8], 1);
    __syncthreads();
    lcur[t] = lh[t] ? atomicAdd(&bcursor[t], lh[t]) : 0;
    __syncthreads();
    for (int i = lo + t; i < hi; i += 256) {
        int d = ei[E + i];
        int p = atomicAdd(&lcur[d >> 8], 1);
        rec_tmp[p] = ((uint_t)ei[i] << 16) | f2bf_rne(ewt[i]);
        dlo_tmp[p] = (uchar_t)(d & 255);
    }
}

// S4: within-bucket counting sort by dst&255 (all in LDS); emit row_ptr+erec.
__global__ void __launch_bounds__(256) bsort_kernel(
        const uint_t* __restrict__ rec_tmp, const uchar_t* __restrict__ dlo_tmp,
        const int* __restrict__ bucket_base, int* __restrict__ row_ptr,
        uint_t* __restrict__ erec, int N, int E) {
    __shared__ int hist[256];
    __shared__ int scn[256];
    __shared__ int cur[256];
    int b = blockIdx.x, t = threadIdx.x;
    int lo = bucket_base[b], hi = bucket_base[b + 1];
    hist[t] = 0;
    __syncthreads();
    for (int i = lo + t; i < hi; i += 256) atomicAdd(&hist[dlo_tmp[i]], 1);
    __syncthreads();
    int v = hist[t];
    scn[t] = v;
    __syncthreads();
    for (int off = 1; off < 256; off <<= 1) {
        int u = (t >= off) ? scn[t - off] : 0;
        __syncthreads();
        scn[t] += u;
        __syncthreads();
    }
    int excl = lo + scn[t] - v;
    int node = (b << 8) + t;
    if (node < N) row_ptr[node] = excl;
    if (b == 0 && t == 0) row_ptr[N] = E;
    cur[t] = excl;
    __syncthreads();
    for (int i = lo + t; i < hi; i += 256) {
        int p = atomicAdd(&cur[dlo_tmp[i]], 1);
        erec[p] = rec_tmp[i];
    }
}

// ---------------------------------------------------------------------------
// 4) APPNP step (bf16 rows): wave per NODE PAIR (A,B) — two independent
//    rec->gather->FMA register chains, software-pipelined so every load's
//    latency sits under the OTHER chain's FMA block:
//      round r: [gathers B_r] [refill recs r+1] [FMA A_r] [gathers A_{r+1}]
//               [FMA B_r]
//    (R10 showed a 20% VALU cut moves dur only 1.5% -> prop is chain-latency
//    bound, not VALU bound; this attacks the chain. R3: guards/nt regress.
//    R6: trip-count perm null. R9: f16 storage overflows — bf16 only.)
//    Tail slots clamp to record 0 (src=0, w=+0.0bf) — row-0 loads are
//    cache-broadcast hits. f32 (packed) accumulate, bf16-RNE out.
// ---------------------------------------------------------------------------
__global__ void __launch_bounds__(256) prop_kernel(
        const ushort_t* __restrict__ xs, ushort_t* __restrict__ xd,
        const ushort_t* __restrict__ h, const int* __restrict__ row_ptr,
        const uint_t* __restrict__ erec, int N) {
    int wid = threadIdx.x >> 6, lane = threadIdx.x & 63;
    int pair = blockIdx.x * 4 + wid;
    int nA = pair * 2;
    if (nA >= N) return;
    int nB = nA + 1;
    bool hasB = (nB < N);
    int rsA = row_ptr[nA], reA = row_ptr[nA + 1];
    int rsB = hasB ? row_ptr[nB] : 0;
    int reB = hasB ? row_ptr[nB + 1] : 0;
    int grp = lane >> 4;        // edge slot 0..3
    int sub = lane & 15;        // dim slot: bf16 elems sub*8 .. sub*8+7

    vf2 accA[4], accB[4];
    #pragma unroll
    for (int i = 0; i < 4; i++) { accA[i] = (vf2)0.f; accB[i] = (vf2)0.f; }

    uint_t rA[8], rB[8];
    uint4  xA_[8], xB_[8];

    // prologue: recs for round 0 (both chains), gathers for chain A round 0
    #pragma unroll
    for (int u = 0; u < 8; u++) {
        int eA = rsA + grp + 4 * u;
        int eB = rsB + grp + 4 * u;
        rA[u] = (eA < reA) ? erec[eA] : 0u;
        rB[u] = (eB < reB) ? erec[eB] : 0u;
    }
    #pragma unroll
    for (int u = 0; u < 8; u++)
        xA_[u] = ((const uint4*)(xs + (size_t)(rA[u] >> 16) * HD))[sub];

    int span = max(reA - rsA, reB - rsB);
    int bA = rsA, bB = rsB;
    for (int done = 0; done < span; done += 32) {
        // weights for this round (extract BEFORE rec refill overwrites)
        float wA[8], wB[8];
        int sB[8];
        #pragma unroll
        for (int u = 0; u < 8; u++) {
            wA[u] = __uint_as_float(rA[u] << 16);   // bf16 -> f32, 1 op
            wB[u] = __uint_as_float(rB[u] << 16);
            sB[u] = (int)(rB[u] >> 16);
        }
        // 1. gathers chain B, this round (latency hidden under FMA A below)
        #pragma unroll
        for (int u = 0; u < 8; u++)
            xB_[u] = ((const uint4*)(xs + (size_t)sB[u] * HD))[sub];
        // 2. refill recs for round r+1 (complete by step 4 / next round)
        #pragma unroll
        for (int u = 0; u < 8; u++) {
            int eA = bA + 32 + grp + 4 * u;
            int eB = bB + 32 + grp + 4 * u;
            rA[u] = (eA < reA) ? erec[eA] : 0u;
            rB[u] = (eB < reB) ? erec[eB] : 0u;
        }
        // 3. FMA chain A (rows gathered last round / prologue)
        #pragma unroll
        for (int u = 0; u < 8; u++) {
            vf2 w2; w2.x = wA[u]; w2.y = wA[u];
            uint4 a = xA_[u];
            vf2 x0; x0.x = bf_lo(a.x); x0.y = bf_hi(a.x);
            vf2 x1; x1.x = bf_lo(a.y); x1.y = bf_hi(a.y);
            vf2 x2; x2.x = bf_lo(a.z); x2.y = bf_hi(a.z);
            vf2 x3; x3.x = bf_lo(a.w); x3.y = bf_hi(a.w);
            accA[0] = pk_fma(w2, x0, accA[0]);
            accA[1] = pk_fma(w2, x1, accA[1]);
            accA[2] = pk_fma(w2, x2, accA[2]);
            accA[3] = pk_fma(w2, x3, accA[3]);
        }
        // 4. gathers chain A for round r+1 (latency hidden under FMA B below)
        #pragma unroll
        for (int u = 0; u < 8; u++)
            xA_[u] = ((const uint4*)(xs + (size_t)(rA[u] >> 16) * HD))[sub];
        // 5. FMA chain B (rows gathered at step 1)
        #pragma unroll
        for (int u = 0; u < 8; u++) {
            vf2 w2; w2.x = wB[u]; w2.y = wB[u];
            uint4 a = xB_[u];
            vf2 x0; x0.x = bf_lo(a.x); x0.y = bf_hi(a.x);
            vf2 x1; x1.x = bf_lo(a.y); x1.y = bf_hi(a.y);
            vf2 x2; x2.x = bf_lo(a.z); x2.y = bf_hi(a.z);
            vf2 x3; x3.x = bf_lo(a.w); x3.y = bf_hi(a.w);
            accB[0] = pk_fma(w2, x0, accB[0]);
            accB[1] = pk_fma(w2, x1, accB[1]);
            accB[2] = pk_fma(w2, x2, accB[2]);
            accB[3] = pk_fma(w2, x3, accB[3]);
        }
        bA += 32; bB += 32;
    }

    float aA[8], aB[8];
    #pragma unroll
    for (int i = 0; i < 4; i++) {
        aA[2 * i] = accA[i].x; aA[2 * i + 1] = accA[i].y;
        aB[2 * i] = accB[i].x; aB[2 * i + 1] = accB[i].y;
    }
    // reduce each chain across the 4 edge groups
    #pragma unroll
    for (int off = 32; off >= 16; off >>= 1) {
        #pragma unroll
        for (int i = 0; i < 8; i++) {
            aA[i] += __shfl_down(aA[i], off);
            aB[i] += __shfl_down(aB[i], off);
        }
    }

    if (grp == 0) {
        uint4 hvA = ((const uint4*)(h + (size_t)nA * HD))[sub];
        float o[8];
        o[0] = 0.9f * aA[0] + 0.1f * bf_lo(hvA.x);
        o[1] = 0.9f * aA[1] + 0.1f * bf_hi(hvA.x);
        o[2] = 0.9f * aA[2] + 0.1f * bf_lo(hvA.y);
        o[3] = 0.9f * aA[3] + 0.1f * bf_hi(hvA.y);
        o[4] = 0.9f * aA[4] + 0.1f * bf_lo(hvA.z);
        o[5] = 0.9f * aA[5] + 0.1f * bf_hi(hvA.z);
        o[6] = 0.9f * aA[6] + 0.1f * bf_lo(hvA.w);
        o[7] = 0.9f * aA[7] + 0.1f * bf_hi(hvA.w);
        uint4 ov;
        ov.x = pack_bf2(o[0], o[1]); ov.y = pack_bf2(o[2], o[3]);
        ov.z = pack_bf2(o[4], o[5]); ov.w = pack_bf2(o[6], o[7]);
        ((uint4*)(xd + (size_t)nA * HD))[sub] = ov;
        if (hasB) {
            uint4 hvB = ((const uint4*)(h + (size_t)nB * HD))[sub];
            float p[8];
            p[0] = 0.9f * aB[0] + 0.1f * bf_lo(hvB.x);
            p[1] = 0.9f * aB[1] + 0.1f * bf_hi(hvB.x);
            p[2] = 0.9f * aB[2] + 0.1f * bf_lo(hvB.y);
            p[3] = 0.9f * aB[3] + 0.1f * bf_hi(hvB.y);
            p[4] = 0.9f * aB[4] + 0.1f * bf_lo(hvB.z);
            p[5] = 0.9f * aB[5] + 0.1f * bf_hi(hvB.z);
            p[6] = 0.9f * aB[6] + 0.1f * bf_lo(hvB.w);
            p[7] = 0.9f * aB[7] + 0.1f * bf_hi(hvB.w);
            uint4 pv;
            pv.x = pack_bf2(p[0], p[1]); pv.y = pack_bf2(p[2], p[3]);
            pv.z = pack_bf2(p[4], p[5]); pv.w = pack_bf2(p[6], p[7]);
            ((uint4*)(xd + (size_t)nB * HD))[sub] = pv;
        }
    }
}

// ---------------------------------------------------------------------------
// 5) Pool: batch is sorted -> running accumulator, atomic only on boundary.
// ---------------------------------------------------------------------------
#define POOL_CHUNK 128
__global__ void pool_kernel(const ushort_t* __restrict__ x, const int* __restrict__ batch,
                            float* __restrict__ pooled, int N) {
    int j = threadIdx.x;
    int n0 = blockIdx.x * POOL_CHUNK;
    if (n0 >= N) return;
    int n1 = min(n0 + POOL_CHUNK, N);
    int cur = batch[n0];
    float acc = 0.f;
    for (int n = n0; n < n1; n++) {
        int g = batch[n];
        if (g != cur) {
            atomicAdd(&pooled[cur * HD + j], acc);
            acc = 0.f; cur = g;
        }
        acc += __uint_as_float(((uint_t)x[(size_t)n * HD + j]) << 16);
    }
    atomicAdd(&pooled[cur * HD + j], acc);
}

// ---------------------------------------------------------------------------
// 6) Head: y = log_softmax(relu(pooled@V0w+V0b) @ V1w + V1b). Block per graph.
// ---------------------------------------------------------------------------
__global__ void head_kernel(const float* __restrict__ pooled, const float* __restrict__ V0w,
                            const float* __restrict__ V0b, const float* __restrict__ V1w,
                            const float* __restrict__ V1b, float* __restrict__ out) {
    __shared__ float prow[HD];
    __shared__ float y1[HD];
    __shared__ float y2[OUTD];
    __shared__ float lse;
    int g = blockIdx.x, j = threadIdx.x;
    prow[j] = pooled[g * HD + j];
    __syncthreads();
    float a = V0b[j];
    for (int d = 0; d < HD; d++) a += prow[d] * V0w[d * HD + j];
    y1[j] = a > 0.f ? a : 0.f;
    __syncthreads();
    if (j < OUTD) {
        float a2 = V1b[j];
        for (int t = 0; t < HD; t++) a2 += y1[t] * V1w[t * OUTD + j];
        y2[j] = a2;
    }
    __syncthreads();
    if (j == 0) {
        float m = y2[0];
        for (int o = 1; o < OUTD; o++) m = fmaxf(m, y2[o]);
        float s = 0.f;
        for (int o = 0; o < OUTD; o++) s += expf(y2[o] - m);
        lse = m + logf(s);
    }
    __syncthreads();
    if (j < OUTD) out[g * OUTD + j] = y2[j] - lse;
}

// ---------------------------------------------------------------------------
extern "C" void kernel_launch(void* const* d_in, const int* in_sizes, int n_in,
                              void* d_out, int out_size, void* d_ws, size_t ws_size,
                              hipStream_t stream) {
    const float* feat = (const float*)d_in[0];
    const float* ewt  = (const float*)d_in[1];
    const float* W1   = (const float*)d_in[2];
    const float* b1   = (const float*)d_in[3];
    const float* W2   = (const float*)d_in[4];
    const float* b2   = (const float*)d_in[5];
    const float* V0w  = (const float*)d_in[6];
    const float* V0b  = (const float*)d_in[7];
    const float* V1w  = (const float*)d_in[8];
    const float* V1b  = (const float*)d_in[9];
    const int*   ei   = (const int*)d_in[10];
    const int*   batch= (const int*)d_in[11];
    const int E = in_sizes[1];
    const int N = in_sizes[11];
    float* out = (float*)d_out;

    char* ws = (char*)d_ws;
    size_t off = 0;
    auto alloc = [&](size_t bytes) -> char* {
        char* p = ws + off;
        off = (off + bytes + 255) & ~(size_t)255;
        return p;
    };
    float*    Wc        = (float*)alloc((size_t)HD * HD * 4);
    float*    bc        = (float*)alloc((size_t)HD * 4);
    ushort_t* hb        = (ushort_t*)alloc((size_t)N * HD * 2);
    ushort_t* xA        = (ushort_t*)alloc((size_t)N * HD * 2);
    ushort_t* xB        = (ushort_t*)alloc((size_t)N * HD * 2);
    float*    pooled    = (float*)alloc((size_t)NG * HD * 4);
    int*      row_ptr   = (int*)alloc((size_t)(N + 1) * 4);
    int*      gbhist    = (int*)alloc((size_t)256 * 4);
    int*      bucket_b  = (int*)alloc((size_t)257 * 4);
    int*      bcursor   = (int*)alloc((size_t)256 * 4);
    uint_t*   rec_tmp   = (uint_t*)alloc((size_t)E * 4);
    uchar_t*  dlo_tmp   = (uchar_t*)alloc((size_t)E);
    uint_t*   erec      = (uint_t*)alloc((size_t)E * 4);
    (void)ws_size;

    hipMemsetAsync(gbhist, 0, (size_t)256 * 4, stream);
    hipMemsetAsync(pooled, 0, (size_t)NG * HD * 4, stream);

    const int NBK    = (N + 255) >> 8;          // dst buckets (<=256 for N<65536)
    const int SBLK   = 256;                     // edge scatter blocks
    const int chunk  = (E + SBLK - 1) / SBLK;   // edges per scatter block

    wc_kernel<<<64, 256, 0, stream>>>(W1, b1, W2, b2, Wc, bc);
    feat_kernel<<<(N + FNT - 1) / FNT, 256, 0, stream>>>(feat, Wc, bc, hb, N);
    bcount_kernel<<<SBLK, 256, 0, stream>>>(ei, gbhist, E, chunk);
    bscan_kernel<<<1, 256, 0, stream>>>(gbhist, bucket_b, bcursor, NBK, E);
    bscatter_kernel<<<SBLK, 256, 0, stream>>>(ei, ewt, bcursor, rec_tmp, dlo_tmp, E, chunk);
    bsort_kernel<<<NBK, 256, 0, stream>>>(rec_tmp, dlo_tmp, bucket_b, row_ptr, erec, N, E);

    const ushort_t* src = hb;
    ushort_t* dst = xA;
    for (int k = 0; k < KSTEPS; k++) {
        prop_kernel<<<(N + 7) / 8, 256, 0, stream>>>(src, dst, hb, row_ptr, erec, N);
        src = dst;
        dst = (dst == xA) ? xB : xA;
    }

    pool_kernel<<<(N + POOL_CHUNK - 1) / POOL_CHUNK, HD, 0, stream>>>(src, batch, pooled, N);
    head_kernel<<<NG, HD, 0, stream>>>(pooled, V0w, V0b, V1w, V1b, out);
}

// Round 12
// 740.752 us; speedup vs baseline: 1.0933x; 1.0933x over previous
//
#include <hip/hip_runtime.h>
#include <hip/hip_fp16.h>
#include <cstdint>

#define HD    128
#define OUTD  10
#define NG    512
#define KSTEPS 10

typedef unsigned short ushort_t;
typedef unsigned int   uint_t;
typedef unsigned char  uchar_t;
typedef float vf2 __attribute__((ext_vector_type(2)));

// bf16 helpers (x/h stored as bf16: REQUIRED — propagated values reach ~1e10,
// f16 overflows at 65504 (R9 failure). f32 accumulate everywhere.)
__device__ __forceinline__ float bf_lo(uint_t u) { return __uint_as_float(u << 16); }
__device__ __forceinline__ float bf_hi(uint_t u) { return __uint_as_float(u & 0xFFFF0000u); }
__device__ __forceinline__ uint_t f2bf_rne(float f) {          // 16-bit result
    uint_t u = __float_as_uint(f);
    return (u + 0x7FFFu + ((u >> 16) & 1u)) >> 16;
}
__device__ __forceinline__ uint_t pack_bf2(float lo, float hi) {
    return f2bf_rne(lo) | (f2bf_rne(hi) << 16);
}

// packed f32 FMA (CDNA VOP3P): d = a*b + c on both lanes of the pair.
__device__ __forceinline__ vf2 pk_fma(vf2 a, vf2 b, vf2 c) {
    vf2 d;
    asm("v_pk_fma_f32 %0, %1, %2, %3" : "=v"(d) : "v"(a), "v"(b), "v"(c));
    return d;
}

// ---------------------------------------------------------------------------
// 1) Collapse the two linear layers: Wc = W1@W2, bc = b1@W2 + b2
// ---------------------------------------------------------------------------
__global__ void wc_kernel(const float* __restrict__ W1, const float* __restrict__ b1,
                          const float* __restrict__ W2, const float* __restrict__ b2,
                          float* __restrict__ Wc, float* __restrict__ bc) {
    int idx = blockIdx.x * 256 + threadIdx.x;      // 0..16383
    int d = idx >> 7, j = idx & 127;
    float s = 0.f;
    for (int t = 0; t < HD; t++) s += W1[d * HD + t] * W2[t * HD + j];
    Wc[idx] = s;
    if (idx < HD) {
        float sb = b2[idx];
        for (int t = 0; t < HD; t++) sb += b1[t] * W2[t * HD + idx];
        bc[idx] = sb;
    }
}

// ---------------------------------------------------------------------------
// 2) h[n][j] = sum_d feat[d][n]*Wc[d][j] + bc[j] -> bf16 [N][128]
//    Register-tiled GEMM, 64 nodes x 128 dims per block (8j x 4n / thread).
//    (R7: FNT=128 -> only 391 blocks -> 14% occupancy; FNT=64 fixed it.)
// ---------------------------------------------------------------------------
#define FNT 64                  // nodes per block
#define FDC 32                  // d-chunk
__global__ void __launch_bounds__(256) feat_kernel(
        const float* __restrict__ feat, const float* __restrict__ Wc,
        const float* __restrict__ bc, ushort_t* __restrict__ h, int N) {
    __shared__ float fch[FDC * FNT];          // [dd][n]  8 KB
    __shared__ float wch[FDC * HD];           // [dd][j] 16 KB
    int t = threadIdx.x;
    int nb0 = blockIdx.x * FNT;
    int tj = t & 15, tn = t >> 4;             // 16 j-groups x 16 n-groups
    int j0 = tj * 8, n0 = tn * 4;             // 8 j x 4 n per thread

    float acc[4][8];
    #pragma unroll
    for (int a = 0; a < 4; a++)
        #pragma unroll
        for (int b = 0; b < 8; b++) acc[a][b] = 0.f;

    for (int dc = 0; dc < HD; dc += FDC) {
        #pragma unroll
        for (int k = 0; k < (FDC * FNT) / 256; k++) {    // 8 iters
            int l = k * 256 + t;
            int dd = l >> 6, n = l & 63;
            int nn = nb0 + n;
            fch[l] = (nn < N) ? feat[(size_t)(dc + dd) * N + nn] : 0.f;
        }
        #pragma unroll
        for (int k = 0; k < (FDC * HD) / 256; k++) {     // 16 iters
            int l = k * 256 + t;
            int dd = l >> 7, j = l & 127;
            wch[l] = Wc[(dc + dd) * HD + j];
        }
        __syncthreads();
        for (int dd = 0; dd < FDC; dd++) {
            const float* fr = &fch[dd * FNT + n0];
            const float* wr = &wch[dd * HD + j0];
            float fv[4], wv[8];
            #pragma unroll
            for (int a = 0; a < 4; a++) fv[a] = fr[a];
            #pragma unroll
            for (int b = 0; b < 8; b++) wv[b] = wr[b];
            #pragma unroll
            for (int a = 0; a < 4; a++)
                #pragma unroll
                for (int b = 0; b < 8; b++) acc[a][b] += fv[a] * wv[b];
        }
        __syncthreads();
    }

    float bv[8];
    #pragma unroll
    for (int b = 0; b < 8; b++) bv[b] = bc[j0 + b];
    #pragma unroll
    for (int a = 0; a < 4; a++) {
        int n = nb0 + n0 + a;
        if (n < N) {
            uint4 ov;
            ov.x = pack_bf2(acc[a][0] + bv[0], acc[a][1] + bv[1]);
            ov.y = pack_bf2(acc[a][2] + bv[2], acc[a][3] + bv[3]);
            ov.z = pack_bf2(acc[a][4] + bv[4], acc[a][5] + bv[5]);
            ov.w = pack_bf2(acc[a][6] + bv[6], acc[a][7] + bv[7]);
            *(uint4*)(h + (size_t)n * HD + j0) = ov;
        }
    }
}

// ---------------------------------------------------------------------------
// 3) CSR build via two-level bucket sort (NO global per-node atomics).
// ---------------------------------------------------------------------------

// S1: global bucket sizes (LDS hist, then one atomic per nonzero bucket/block)
__global__ void __launch_bounds__(256) bcount_kernel(
        const int* __restrict__ ei, int* __restrict__ gbhist, int E, int chunk) {
    __shared__ int lh[256];
    int b = blockIdx.x, t = threadIdx.x;
    lh[t] = 0;
    __syncthreads();
    int lo = b * chunk, hi = min(E, lo + chunk);
    for (int i = lo + t; i < hi; i += 256) atomicAdd(&lh[ei[E + i] >> 8], 1);
    __syncthreads();
    if (lh[t]) atomicAdd(&gbhist[t], lh[t]);
}

// S2: exclusive scan of bucket sizes -> bucket_base[0..NBK], bcursor init
__global__ void bscan_kernel(const int* __restrict__ gbhist, int* __restrict__ bucket_base,
                             int* __restrict__ bcursor, int NBK, int E) {
    __shared__ int sm[256];
    int t = threadIdx.x;
    int v = (t < NBK) ? gbhist[t] : 0;
    sm[t] = v;
    __syncthreads();
    for (int off = 1; off < 256; off <<= 1) {
        int u = (t >= off) ? sm[t - off] : 0;
        __syncthreads();
        sm[t] += u;
        __syncthreads();
    }
    int excl = sm[t] - v;
    if (t < NBK) { bucket_base[t] = excl; bcursor[t] = excl; }
    if (t == 0) bucket_base[NBK] = E;
}

// S3: scatter edges into bucket-ordered intermediate (rec + low-byte of dst).
// Record: (src << 16) | bf16(weight) — bf16 w decodes with ONE shift in prop.
__global__ void __launch_bounds__(256) bscatter_kernel(
        const int* __restrict__ ei, const float* __restrict__ ewt,
        int* __restrict__ bcursor, uint_t* __restrict__ rec_tmp,
        uchar_t* __restrict__ dlo_tmp, int E, int chunk) {
    __shared__ int lh[256];
    __shared__ int lcur[256];
    int b = blockIdx.x, t = threadIdx.x;
    lh[t] = 0;
    __syncthreads();
    int lo = b * chunk, hi = min(E, lo + chunk);
    for (int i = lo + t; i < hi; i += 256) atomicAdd(&lh[ei[E + i] >> 8], 1);
    __syncthreads();
    lcur[t] = lh[t] ? atomicAdd(&bcursor[t], lh[t]) : 0;
    __syncthreads();
    for (int i = lo + t; i < hi; i += 256) {
        int d = ei[E + i];
        int p = atomicAdd(&lcur[d >> 8], 1);
        rec_tmp[p] = ((uint_t)ei[i] << 16) | f2bf_rne(ewt[i]);
        dlo_tmp[p] = (uchar_t)(d & 255);
    }
}

// S4: within-bucket counting sort by dst&255 (all in LDS); emit row_ptr+erec.
__global__ void __launch_bounds__(256) bsort_kernel(
        const uint_t* __restrict__ rec_tmp, const uchar_t* __restrict__ dlo_tmp,
        const int* __restrict__ bucket_base, int* __restrict__ row_ptr,
        uint_t* __restrict__ erec, int N, int E) {
    __shared__ int hist[256];
    __shared__ int scn[256];
    __shared__ int cur[256];
    int b = blockIdx.x, t = threadIdx.x;
    int lo = bucket_base[b], hi = bucket_base[b + 1];
    hist[t] = 0;
    __syncthreads();
    for (int i = lo + t; i < hi; i += 256) atomicAdd(&hist[dlo_tmp[i]], 1);
    __syncthreads();
    int v = hist[t];
    scn[t] = v;
    __syncthreads();
    for (int off = 1; off < 256; off <<= 1) {
        int u = (t >= off) ? scn[t - off] : 0;
        __syncthreads();
        scn[t] += u;
        __syncthreads();
    }
    int excl = lo + scn[t] - v;
    int node = (b << 8) + t;
    if (node < N) row_ptr[node] = excl;
    if (b == 0 && t == 0) row_ptr[N] = E;
    cur[t] = excl;
    __syncthreads();
    for (int i = lo + t; i < hi; i += 256) {
        int p = atomicAdd(&cur[dlo_tmp[i]], 1);
        erec[p] = rec_tmp[i];
    }
}

// ---------------------------------------------------------------------------
// 4) APPNP step (bf16 rows): ONE node per wave (R11's pairing regressed:
//    max(degA,degB) imbalance +15%, VGPR 76). 4 groups x 16 lanes; 16-edge
//    half-rounds, ping-pong register sets: while FMA'ing round r, round
//    r+1's row gathers (issued last round) are in flight and round r+2's
//    records are fetching. Poisson(32) deg -> ~2 rounds/node, so nearly
//    every node's gather latency hides under its own FMA work.
//    h-row load hoisted to wave start (was serial in epilogue).
//    Tail slots clamp to record 0 (src=0, w=+0.0bf): row-0 loads are
//    cache-broadcast hits. pk_fma f32 accumulate, bf16-RNE out.
//    (R10: VALU cut null -> chain-latency bound. R6: trip-balance null.
//    R3: gather guards + nt loads regress. R9: f16 storage overflows.)
// ---------------------------------------------------------------------------
#define PU 4     // edges per group per half-round (16 edges/round)
__global__ void __launch_bounds__(256) prop_kernel(
        const ushort_t* __restrict__ xs, ushort_t* __restrict__ xd,
        const ushort_t* __restrict__ h, const int* __restrict__ row_ptr,
        const uint_t* __restrict__ erec, int N) {
    int wid = threadIdx.x >> 6, lane = threadIdx.x & 63;
    int node = blockIdx.x * 4 + wid;
    if (node >= N) return;
    int rs = row_ptr[node], re = row_ptr[node + 1];
    int grp = lane >> 4;        // edge slot 0..3
    int sub = lane & 15;        // dim slot: bf16 elems sub*8 .. sub*8+7

    // hoisted teleport-row load: latency hides under the whole edge loop
    uint4 hv = make_uint4(0u, 0u, 0u, 0u);
    if (grp == 0) hv = ((const uint4*)(h + (size_t)node * HD))[sub];

    vf2 acc2[4];
    #pragma unroll
    for (int i = 0; i < 4; i++) acc2[i] = (vf2)0.f;

    uint_t recA[PU], recB[PU];
    uint4  rowA[PU], rowB[PU];

    // prologue: round0 recs -> rows; round1 recs
    #pragma unroll
    for (int u = 0; u < PU; u++) {
        int e = rs + grp + 4 * u;
        recA[u] = (e < re) ? erec[e] : 0u;
    }
    #pragma unroll
    for (int u = 0; u < PU; u++)
        rowA[u] = ((const uint4*)(xs + (size_t)(recA[u] >> 16) * HD))[sub];
    #pragma unroll
    for (int u = 0; u < PU; u++) {
        int e = rs + 16 + grp + 4 * u;
        recB[u] = (e < re) ? erec[e] : 0u;
    }

    int base = rs;
    for (;;) {
        // ---- half-round: A current ----
        #pragma unroll
        for (int u = 0; u < PU; u++)            // issue next round's gathers
            rowB[u] = ((const uint4*)(xs + (size_t)(recB[u] >> 16) * HD))[sub];
        float wA[PU];
        #pragma unroll
        for (int u = 0; u < PU; u++) wA[u] = __uint_as_float(recA[u] << 16);
        #pragma unroll
        for (int u = 0; u < PU; u++) {          // recs for round base+32
            int e = base + 32 + grp + 4 * u;
            recA[u] = (e < re) ? erec[e] : 0u;
        }
        #pragma unroll
        for (int u = 0; u < PU; u++) {          // FMA current rows
            vf2 w2; w2.x = wA[u]; w2.y = wA[u];
            uint4 a = rowA[u];
            vf2 x0; x0.x = bf_lo(a.x); x0.y = bf_hi(a.x);
            vf2 x1; x1.x = bf_lo(a.y); x1.y = bf_hi(a.y);
            vf2 x2; x2.x = bf_lo(a.z); x2.y = bf_hi(a.z);
            vf2 x3; x3.x = bf_lo(a.w); x3.y = bf_hi(a.w);
            acc2[0] = pk_fma(w2, x0, acc2[0]);
            acc2[1] = pk_fma(w2, x1, acc2[1]);
            acc2[2] = pk_fma(w2, x2, acc2[2]);
            acc2[3] = pk_fma(w2, x3, acc2[3]);
        }
        base += 16;
        if (base >= re) break;
        // ---- half-round: B current (mirror) ----
        #pragma unroll
        for (int u = 0; u < PU; u++)
            rowA[u] = ((const uint4*)(xs + (size_t)(recA[u] >> 16) * HD))[sub];
        float wB[PU];
        #pragma unroll
        for (int u = 0; u < PU; u++) wB[u] = __uint_as_float(recB[u] << 16);
        #pragma unroll
        for (int u = 0; u < PU; u++) {
            int e = base + 32 + grp + 4 * u;
            recB[u] = (e < re) ? erec[e] : 0u;
        }
        #pragma unroll
        for (int u = 0; u < PU; u++) {
            vf2 w2; w2.x = wB[u]; w2.y = wB[u];
            uint4 a = rowB[u];
            vf2 x0; x0.x = bf_lo(a.x); x0.y = bf_hi(a.x);
            vf2 x1; x1.x = bf_lo(a.y); x1.y = bf_hi(a.y);
            vf2 x2; x2.x = bf_lo(a.z); x2.y = bf_hi(a.z);
            vf2 x3; x3.x = bf_lo(a.w); x3.y = bf_hi(a.w);
            acc2[0] = pk_fma(w2, x0, acc2[0]);
            acc2[1] = pk_fma(w2, x1, acc2[1]);
            acc2[2] = pk_fma(w2, x2, acc2[2]);
            acc2[3] = pk_fma(w2, x3, acc2[3]);
        }
        base += 16;
        if (base >= re) break;
    }

    float acc[8];
    #pragma unroll
    for (int i = 0; i < 4; i++) { acc[2 * i] = acc2[i].x; acc[2 * i + 1] = acc2[i].y; }

    // reduce across the 4 edge groups
    #pragma unroll
    for (int off = 32; off >= 16; off >>= 1) {
        #pragma unroll
        for (int i = 0; i < 8; i++) acc[i] += __shfl_down(acc[i], off);
    }

    if (grp == 0) {
        float o[8];
        o[0] = 0.9f * acc[0] + 0.1f * bf_lo(hv.x);
        o[1] = 0.9f * acc[1] + 0.1f * bf_hi(hv.x);
        o[2] = 0.9f * acc[2] + 0.1f * bf_lo(hv.y);
        o[3] = 0.9f * acc[3] + 0.1f * bf_hi(hv.y);
        o[4] = 0.9f * acc[4] + 0.1f * bf_lo(hv.z);
        o[5] = 0.9f * acc[5] + 0.1f * bf_hi(hv.z);
        o[6] = 0.9f * acc[6] + 0.1f * bf_lo(hv.w);
        o[7] = 0.9f * acc[7] + 0.1f * bf_hi(hv.w);
        uint4 ov;
        ov.x = pack_bf2(o[0], o[1]);
        ov.y = pack_bf2(o[2], o[3]);
        ov.z = pack_bf2(o[4], o[5]);
        ov.w = pack_bf2(o[6], o[7]);
        ((uint4*)(xd + (size_t)node * HD))[sub] = ov;
    }
}

// ---------------------------------------------------------------------------
// 5) Pool: batch is sorted -> running accumulator, atomic only on boundary.
// ---------------------------------------------------------------------------
#define POOL_CHUNK 128
__global__ void pool_kernel(const ushort_t* __restrict__ x, const int* __restrict__ batch,
                            float* __restrict__ pooled, int N) {
    int j = threadIdx.x;
    int n0 = blockIdx.x * POOL_CHUNK;
    if (n0 >= N) return;
    int n1 = min(n0 + POOL_CHUNK, N);
    int cur = batch[n0];
    float acc = 0.f;
    for (int n = n0; n < n1; n++) {
        int g = batch[n];
        if (g != cur) {
            atomicAdd(&pooled[cur * HD + j], acc);
            acc = 0.f; cur = g;
        }
        acc += __uint_as_float(((uint_t)x[(size_t)n * HD + j]) << 16);
    }
    atomicAdd(&pooled[cur * HD + j], acc);
}

// ---------------------------------------------------------------------------
// 6) Head: y = log_softmax(relu(pooled@V0w+V0b) @ V1w + V1b). Block per graph.
// ---------------------------------------------------------------------------
__global__ void head_kernel(const float* __restrict__ pooled, const float* __restrict__ V0w,
                            const float* __restrict__ V0b, const float* __restrict__ V1w,
                            const float* __restrict__ V1b, float* __restrict__ out) {
    __shared__ float prow[HD];
    __shared__ float y1[HD];
    __shared__ float y2[OUTD];
    __shared__ float lse;
    int g = blockIdx.x, j = threadIdx.x;
    prow[j] = pooled[g * HD + j];
    __syncthreads();
    float a = V0b[j];
    for (int d = 0; d < HD; d++) a += prow[d] * V0w[d * HD + j];
    y1[j] = a > 0.f ? a : 0.f;
    __syncthreads();
    if (j < OUTD) {
        float a2 = V1b[j];
        for (int t = 0; t < HD; t++) a2 += y1[t] * V1w[t * OUTD + j];
        y2[j] = a2;
    }
    __syncthreads();
    if (j == 0) {
        float m = y2[0];
        for (int o = 1; o < OUTD; o++) m = fmaxf(m, y2[o]);
        float s = 0.f;
        for (int o = 0; o < OUTD; o++) s += expf(y2[o] - m);
        lse = m + logf(s);
    }
    __syncthreads();
    if (j < OUTD) out[g * OUTD + j] = y2[j] - lse;
}

// ---------------------------------------------------------------------------
extern "C" void kernel_launch(void* const* d_in, const int* in_sizes, int n_in,
                              void* d_out, int out_size, void* d_ws, size_t ws_size,
                              hipStream_t stream) {
    const float* feat = (const float*)d_in[0];
    const float* ewt  = (const float*)d_in[1];
    const float* W1   = (const float*)d_in[2];
    const float* b1   = (const float*)d_in[3];
    const float* W2   = (const float*)d_in[4];
    const float* b2   = (const float*)d_in[5];
    const float* V0w  = (const float*)d_in[6];
    const float* V0b  = (const float*)d_in[7];
    const float* V1w  = (const float*)d_in[8];
    const float* V1b  = (const float*)d_in[9];
    const int*   ei   = (const int*)d_in[10];
    const int*   batch= (const int*)d_in[11];
    const int E = in_sizes[1];
    const int N = in_sizes[11];
    float* out = (float*)d_out;

    char* ws = (char*)d_ws;
    size_t off = 0;
    auto alloc = [&](size_t bytes) -> char* {
        char* p = ws + off;
        off = (off + bytes + 255) & ~(size_t)255;
        return p;
    };
    float*    Wc        = (float*)alloc((size_t)HD * HD * 4);
    float*    bc        = (float*)alloc((size_t)HD * 4);
    ushort_t* hb        = (ushort_t*)alloc((size_t)N * HD * 2);
    ushort_t* xA        = (ushort_t*)alloc((size_t)N * HD * 2);
    ushort_t* xB        = (ushort_t*)alloc((size_t)N * HD * 2);
    float*    pooled    = (float*)alloc((size_t)NG * HD * 4);
    int*      row_ptr   = (int*)alloc((size_t)(N + 1) * 4);
    int*      gbhist    = (int*)alloc((size_t)256 * 4);
    int*      bucket_b  = (int*)alloc((size_t)257 * 4);
    int*      bcursor   = (int*)alloc((size_t)256 * 4);
    uint_t*   rec_tmp   = (uint_t*)alloc((size_t)E * 4);
    uchar_t*  dlo_tmp   = (uchar_t*)alloc((size_t)E);
    uint_t*   erec      = (uint_t*)alloc((size_t)E * 4);
    (void)ws_size;

    hipMemsetAsync(gbhist, 0, (size_t)256 * 4, stream);
    hipMemsetAsync(pooled, 0, (size_t)NG * HD * 4, stream);

    const int NBK    = (N + 255) >> 8;          // dst buckets (<=256 for N<65536)
    const int SBLK   = 256;                     // edge scatter blocks
    const int chunk  = (E + SBLK - 1) / SBLK;   // edges per scatter block

    wc_kernel<<<64, 256, 0, stream>>>(W1, b1, W2, b2, Wc, bc);
    feat_kernel<<<(N + FNT - 1) / FNT, 256, 0, stream>>>(feat, Wc, bc, hb, N);
    bcount_kernel<<<SBLK, 256, 0, stream>>>(ei, gbhist, E, chunk);
    bscan_kernel<<<1, 256, 0, stream>>>(gbhist, bucket_b, bcursor, NBK, E);
    bscatter_kernel<<<SBLK, 256, 0, stream>>>(ei, ewt, bcursor, rec_tmp, dlo_tmp, E, chunk);
    bsort_kernel<<<NBK, 256, 0, stream>>>(rec_tmp, dlo_tmp, bucket_b, row_ptr, erec, N, E);

    const ushort_t* src = hb;
    ushort_t* dst = xA;
    for (int k = 0; k < KSTEPS; k++) {
        prop_kernel<<<(N + 3) / 4, 256, 0, stream>>>(src, dst, hb, row_ptr, erec, N);
        src = dst;
        dst = (dst == xA) ? xB : xA;
    }

    pool_kernel<<<(N + POOL_CHUNK - 1) / POOL_CHUNK, HD, 0, stream>>>(src, batch, pooled, N);
    head_kernel<<<NG, HD, 0, stream>>>(pooled, V0w, V0b, V1w, V1b, out);
}